// Round 3
// baseline (335.974 us; speedup 1.0000x reference)
//
#include <hip/hip_runtime.h>

// r17: attack the two measured bottlenecks of r16 (335us):
//  (a) head_kernel 60us @ VALUBusy 6% (latency-bound): rewritten as 192 blocks
//      x 16 vox, h->LDS fp32, 32 independent fmaf chains in GEMM2, w2 load
//      shared across 4 vox (98->25MB L2 traffic), logits staged [co][vox]
//      stride-20 in LDS so score writes are full 64B lines (12.4->6.5MB).
//  (b) conv ~25us/launch @ 1 block/CU: K split over 8 groups (2 blocks x
//      4 waves) of 54 K-atoms (tap x ci-half, K=32 each). Grid/job 64->128,
//      in-loop 384-512 blocks = 2 blocks/CU. Blocks write partial sums;
//      gates sums the two partials + bias. Weights prepacked per-atom
//      [tap][hs][64co][8 chunks ^ (co&7)][8] f16 hi/lo (x64 scale), so conv
//      staging is a linear coalesced copy; 8KB atom tiles, double-buffered.
// Numerics unchanged: 3-segment hi/lo f16 MFMA (fp32-grade, ~2^-22).

typedef _Float16 f16;
typedef _Float16 f16x8 __attribute__((ext_vector_type(8)));
typedef float    f32x4 __attribute__((ext_vector_type(4)));

#define WSTRIDE 442368   // fp32 weight elements per layer: 27*64*256
#define WPT     884736   // halfs per packed tensor: 54*256*64
#define XSP     65536    // halfs per s-slab of h: 512*128
#define HSP     458752   // halfs per nc of h: 7*512*128
#define GPART   262144   // floats per conv partial buffer: 2*512*256

__device__ __forceinline__ float wred_sum(float v) {
    #pragma unroll
    for (int o = 32; o > 0; o >>= 1) v += __shfl_down(v, o, 64);
    return __shfl(v, 0, 64);
}
__device__ __forceinline__ float fsig(float x)  { return 1.f / (1.f + __expf(-x)); }
__device__ __forceinline__ float ftanh(float x) { return 1.f - 2.f / (__expf(2.f*x) + 1.f); }

// h[nc][s][vox][128] = hi/lo split of emb[tok][ch]
__global__ __launch_bounds__(256) void embed_kernel(
    const int* __restrict__ code, const int* __restrict__ ncode,
    const float* __restrict__ emb, f16* __restrict__ h)
{
    int e = blockIdx.x * 256 + threadIdx.x;   // < 458752
    int ch = e & 63;
    int pos = e >> 6;            // nc*7*512 + s*512 + vox
    int vox = pos & 511;
    int t = pos >> 9;
    int s = t % 7, nc = t / 7;
    int tok = (s < 5) ? code[(nc*5 + s)*512 + vox]
                      : ncode[(nc*3 + (s-5))*512 + vox];
    float x = emb[tok*64 + ch];
    f16 hi = (f16)x;
    h[(size_t)pos*128 + ch]      = hi;
    h[(size_t)pos*128 + 64 + ch] = (f16)(x - (float)hi);
}

// Pack weights: src [27][64 ci][256 co] fp32 -> per K-atom (tap, hs=ci-half)
// [54 atoms][256 co][8 chunks][8] f16, hi chunks at (j ^ (co&7)), lo at
// ((4+j) ^ (co&7)), values scaled x64. Tensor order: win0, wh0, win1, wh1.
__global__ __launch_bounds__(256) void wsplit_kernel(
    const float* __restrict__ win, const float* __restrict__ wh,
    f16* __restrict__ wp)
{
    int b = blockIdx.x;               // 108 = 4 tensors * 27 taps
    int tensor = b / 27, tap = b % 27;
    const float* src = ((tensor & 1) ? wh : win) + (tensor >> 1) * WSTRIDE
                     + tap * 16384;
    int co = threadIdx.x;
    int sw = co & 7;
    #pragma unroll
    for (int hs = 0; hs < 2; ++hs) {
        f16* dst = wp + (((size_t)tensor*27 + tap)*2 + hs)*16384 + co*64;
        #pragma unroll
        for (int j = 0; j < 4; ++j) {
            f16x8 hi8, lo8;
            #pragma unroll
            for (int m = 0; m < 8; ++m) {
                float w = src[(hs*32 + j*8 + m)*256 + co] * 64.f;
                f16 hv = (f16)w;
                hi8[m] = hv;
                lo8[m] = (f16)(w - (float)hv);
            }
            *(f16x8*)(dst + ((j     ^ sw))*8) = hi8;
            *(f16x8*)(dst + (((4+j) ^ sw))*8) = lo8;
        }
    }
}

struct MJob { const f16* x; const f16* w; float* y; };
struct MJobs { MJob j[4]; };

// One 3x3x3 SAME conv job (Cin=64 -> Cout=256), implicit GEMM, 3-segment
// hi/lo f16 MFMA. grid.x = 128/job: [kb(2)|slab(2)|u(8)|cog(4)]. The 54
// K-atoms are split over 8 groups = kb*4+wid ({7x6,6x2}); each wave stages
// its atom's [64co][64ci'] tile (8KB) into a private double-buffered LDS
// region. A-frags straight from global with halo predication. One barrier;
// in-block 4-way K-reduce; block writes partial to y + kb*GPART (no bias).
__global__ __launch_bounds__(256, 2) void conv_mfma_kernel(MJobs js)
{
    const MJob J = js.j[blockIdx.y];
    __shared__ float4 smem[4096];          // 64 KiB
    f16* wbuf = (f16*)smem;

    const int bx = blockIdx.x;
    const int cog = bx & 3, u = (bx >> 2) & 7, slab = (bx >> 5) & 1, kb = bx >> 6;
    const int t = threadIdx.x, wid = t >> 6, l = t & 63;
    const int lv = (l >> 3) & 1, lw = l & 7, khi = l >> 4;

    const int gid = kb*4 + wid;
    const int g0  = (gid < 6) ? gid*7 : 42 + (gid - 6)*6;
    const int cnt = (gid < 6) ? 7 : 6;

    const f16* xbase = J.x + (size_t)slab * HSP;
    const f16* wjob  = J.w + (size_t)cog * 4096;      // + atom*16384
    f16* wmine = wbuf + wid * 8192;                   // dbuf 2 x 4096 halfs

    f16x8 wreg[8];
    auto wload = [&](int k) {             // global -> regs (linear, coalesced)
        const f16* src = wjob + (size_t)k * 16384 + l * 8;
        #pragma unroll
        for (int i = 0; i < 8; ++i) wreg[i] = *(const f16x8*)(src + i * 512);
    };
    auto wstore = [&](int b) {            // regs -> LDS (linear)
        f16* dst = wmine + b * 4096 + l * 8;
        #pragma unroll
        for (int i = 0; i < 8; ++i) *(f16x8*)(dst + i * 512) = wreg[i];
    };

    wload(g0); wstore(0);

    f32x4 acc[4][4] = {};                 // [a: vox 16-tile][n: co 16-tile]
    int cur = 0;
    for (int q = 0; q < cnt; ++q) {
        const int k = g0 + q;
        if (q + 1 < cnt) wload(k + 1);              // prefetch next atom
        const int tap = k >> 1, hs = k & 1;
        const int du = tap / 9, rr = tap % 9, dv = rr / 3, dw = rr % 3;
        const int uu = u + du - 1;
        const bool uok = (unsigned)uu < 8u;
        const f16* xrow[4]; bool ok[4];
        #pragma unroll
        for (int a = 0; a < 4; ++a) {               // vox = a*16 + (l&15)
            int vs = a*2 + lv + dv - 1, ws = lw + dw - 1;
            ok[a] = uok && (unsigned)vs < 8u && (unsigned)ws < 8u;
            xrow[a] = xbase + ((size_t)(uu*64 + vs*8 + ws) << 7) + khi*8;
        }
        const f16* wrow = wmine + cur*4096 + (l & 15)*64;
        const int schi = ((khi    ) ^ lw) * 8;
        const int sclo = ((4 + khi) ^ lw) * 8;
        f16x8 ahi[4], alo[4], bhi[4], blo[4];
        #pragma unroll
        for (int a = 0; a < 4; ++a) {
            f16x8 v = {0,0,0,0,0,0,0,0}, v2 = v;
            if (ok[a]) {
                v  = *(const f16x8*)(xrow[a] + hs*32);
                v2 = *(const f16x8*)(xrow[a] + 64 + hs*32);
            }
            ahi[a] = v; alo[a] = v2;
        }
        #pragma unroll
        for (int n = 0; n < 4; ++n) {
            bhi[n] = *(const f16x8*)(wrow + n*1024 + schi);
            blo[n] = *(const f16x8*)(wrow + n*1024 + sclo);
        }
        #pragma unroll
        for (int a = 0; a < 4; ++a)
            #pragma unroll
            for (int n = 0; n < 4; ++n)
                acc[a][n] = __builtin_amdgcn_mfma_f32_16x16x32_f16(
                    ahi[a], bhi[n], acc[a][n], 0, 0, 0);
        #pragma unroll
        for (int a = 0; a < 4; ++a)
            #pragma unroll
            for (int n = 0; n < 4; ++n)
                acc[a][n] = __builtin_amdgcn_mfma_f32_16x16x32_f16(
                    alo[a], bhi[n], acc[a][n], 0, 0, 0);
        #pragma unroll
        for (int a = 0; a < 4; ++a)
            #pragma unroll
            for (int n = 0; n < 4; ++n)
                acc[a][n] = __builtin_amdgcn_mfma_f32_16x16x32_f16(
                    ahi[a], blo[n], acc[a][n], 0, 0, 0);
        if (q + 1 < cnt) { wstore(cur ^ 1); cur ^= 1; }
    }

    // In-block 4-way K-reduction: each wave dumps over its OWN 16KB region.
    f32x4* red = (f32x4*)smem;
    {
        f32x4* mine = red + (size_t)(wid * 64 + l) * 16;
        #pragma unroll
        for (int a = 0; a < 4; ++a)
            #pragma unroll
            for (int n = 0; n < 4; ++n)
                mine[(a * 4 + n) ^ (l & 15)] = acc[a][n];
    }
    __syncthreads();
    {
        float* yp = J.y + (size_t)kb * GPART;
        const int a = t >> 6, ll = t & 63;
        #pragma unroll
        for (int n = 0; n < 4; ++n) {
            const int ch = (a * 4 + n) ^ (ll & 15);
            f32x4 sv = red[(0 * 64 + ll) * 16 + ch]
                     + red[(1 * 64 + ll) * 16 + ch]
                     + red[(2 * 64 + ll) * 16 + ch]
                     + red[(3 * 64 + ll) * 16 + ch];
            const int co = cog * 64 + n * 16 + (ll & 15);
            #pragma unroll
            for (int r = 0; r < 4; ++r) {           // D row = 4*(ll>>4)+r
                int vox = a * 16 + (ll >> 4) * 4 + r;
                yp[(size_t)(slab * 512 + u * 64 + vox) * 256 + co]
                    = sv[r] * 0.015625f;            // /64 (w' scale)
            }
        }
    }
}

// Dual-LN LSTM cell (fp32). Sums the two conv partials + bias per path.
struct GJob {
    const float* giA; const float* giB;
    const float* ghA; const float* ghB;
    const float* bin; const float* bhb;
    const float* ginw; const float* ginb;
    const float* ghw;  const float* ghb;
    float* cx; f16* h16; int k; int k0;
};
__global__ __launch_bounds__(256) void gates_step_kernel(GJob ja, GJob jb)
{
    const GJob J = (blockIdx.y == 0) ? ja : jb;
    const int wid = threadIdx.x >> 6, lane = threadIdx.x & 63;
    const int row = blockIdx.x * 4 + wid;     // nc*512 + vox, < 1024
    const int nc = row >> 9, vox = row & 511;

    const float* gA = J.giA + (size_t)row*256;
    const float* gB = J.giB + (size_t)row*256;
    float a0 = gA[lane]     + gB[lane]     + J.bin[lane];
    float a1 = gA[64+lane]  + gB[64+lane]  + J.bin[64+lane];
    float a2 = gA[128+lane] + gB[128+lane] + J.bin[128+lane];
    float a3 = gA[192+lane] + gB[192+lane] + J.bin[192+lane];
    float mu1 = wred_sum(a0+a1+a2+a3) * (1.f/256.f);
    float d0=a0-mu1, d1=a1-mu1, d2=a2-mu1, d3=a3-mu1;
    float v1 = wred_sum(d0*d0+d1*d1+d2*d2+d3*d3) * (1.f/256.f);
    float rs1 = rsqrtf(v1 + 1e-5f);

    float b0, b1, b2, b3;
    if (J.k0) {
        b0 = J.bhb[lane]; b1 = J.bhb[64+lane];
        b2 = J.bhb[128+lane]; b3 = J.bhb[192+lane];
    } else {
        const float* hA = J.ghA + (size_t)row*256;
        const float* hB = J.ghB + (size_t)row*256;
        b0 = hA[lane]     + hB[lane]     + J.bhb[lane];
        b1 = hA[64+lane]  + hB[64+lane]  + J.bhb[64+lane];
        b2 = hA[128+lane] + hB[128+lane] + J.bhb[128+lane];
        b3 = hA[192+lane] + hB[192+lane] + J.bhb[192+lane];
    }
    float mu2 = wred_sum(b0+b1+b2+b3) * (1.f/256.f);
    float e0=b0-mu2, e1=b1-mu2, e2=b2-mu2, e3=b3-mu2;
    float v2 = wred_sum(e0*e0+e1*e1+e2*e2+e3*e3) * (1.f/256.f);
    float rs2 = rsqrtf(v2 + 1e-5f);

    float Ig = d0*rs1*J.ginw[lane]     + J.ginb[lane]     + e0*rs2*J.ghw[lane]     + J.ghb[lane];
    float Fg = d1*rs1*J.ginw[64+lane]  + J.ginb[64+lane]  + e1*rs2*J.ghw[64+lane]  + J.ghb[64+lane];
    float Cg = d2*rs1*J.ginw[128+lane] + J.ginb[128+lane] + e2*rs2*J.ghw[128+lane] + J.ghb[128+lane];
    float Og = d3*rs1*J.ginw[192+lane] + J.ginb[192+lane] + e3*rs2*J.ghw[192+lane] + J.ghb[192+lane];

    float c_old = J.k0 ? 0.f : J.cx[(size_t)row*64 + lane];
    float c_new = fsig(Fg)*c_old + fsig(Ig)*ftanh(Cg);
    float h_new = fsig(Og)*ftanh(c_new);
    J.cx[(size_t)row*64 + lane] = c_new;
    size_t hb = ((size_t)(nc*7 + J.k)*512 + vox)*128 + lane;
    f16 hi = (f16)h_new;
    J.h16[hb]      = hi;
    J.h16[hb + 64] = (f16)(h_new - (float)hi);
}

// Head: 192 blocks x 16 vox (4 per wave). h reconstructed to fp32 in LDS;
// GEMV1 dual-accumulator; GEMM2 shares each w2 load across 4 vox with 32
// independent chains/lane; logits staged [co][16 vox] stride-20 in LDS so
// score writes are full 64B lines.
__global__ __launch_bounds__(256) void head_kernel(
    const f16* __restrict__ h,        // [2][7][512][128] hi/lo
    const float* __restrict__ w1, const float* __restrict__ b1,
    const float* __restrict__ lng, const float* __restrict__ lnb,
    const float* __restrict__ w2, const float* __restrict__ b2,
    const int* __restrict__ ncode,
    float* __restrict__ out)
{
    __shared__ float hsm[16][64];
    __shared__ float zv[16][64];
    __shared__ float lg[10240];               // [512 co][16 vox] stride 20
    const int blk = blockIdx.x;               // 192 = n(2) x sn(3) x vg(32)
    const int n = blk / 96;
    const int sn = (blk / 32) % 3;
    const int vox0 = (blk & 31) * 16;
    const int t = threadIdx.x, wid = t >> 6, lane = t & 63;

    for (int idx = t; idx < 1024; idx += 256) {
        int vr = idx >> 6, ch = idx & 63;
        const f16* hv = h + (size_t)((n*7 + sn + 4)*512 + vox0 + vr)*128;
        hsm[vr][ch] = (float)hv[ch] + (float)hv[64 + ch];
    }
    __syncthreads();

    // GEMV1 (h @ w1 + b1) for this wave's 4 vox, dual accumulators
    float yva[4], yvb[4];
    #pragma unroll
    for (int r = 0; r < 4; ++r) { yva[r] = b1[lane]; yvb[r] = 0.f; }
    for (int kk = 0; kk < 64; kk += 2) {
        float w1a = w1[kk*64 + lane], w1b = w1[(kk+1)*64 + lane];
        #pragma unroll
        for (int r = 0; r < 4; ++r) {
            yva[r] = fmaf(hsm[wid*4 + r][kk],     w1a, yva[r]);
            yvb[r] = fmaf(hsm[wid*4 + r][kk + 1], w1b, yvb[r]);
        }
    }
    #pragma unroll
    for (int r = 0; r < 4; ++r) {
        float yv = yva[r] + yvb[r];
        float mu = wred_sum(yv) * (1.f/64.f);
        float d = yv - mu;
        float var = wred_sum(d*d) * (1.f/64.f);
        float ln = d * rsqrtf(var + 1e-5f) * lng[lane] + lnb[lane];
        zv[wid*4 + r][lane] = 0.5f * ln * (1.f + erff(ln * 0.70710678118654752f));
    }
    __syncthreads();

    // GEMM2: logits[4 vox][512 co]
    float l[4][8];
    #pragma unroll
    for (int r = 0; r < 4; ++r)
        #pragma unroll
        for (int j = 0; j < 8; ++j) l[r][j] = b2[j*64 + lane];
    for (int kk = 0; kk < 64; ++kk) {
        float wv[8];
        #pragma unroll
        for (int j = 0; j < 8; ++j) wv[j] = w2[kk*512 + j*64 + lane];
        #pragma unroll
        for (int r = 0; r < 4; ++r) {
            float zz = zv[wid*4 + r][kk];
            #pragma unroll
            for (int j = 0; j < 8; ++j) l[r][j] = fmaf(zz, wv[j], l[r][j]);
        }
    }
    #pragma unroll
    for (int r = 0; r < 4; ++r)
        #pragma unroll
        for (int j = 0; j < 8; ++j)
            lg[(j*64 + lane)*20 + wid*4 + r] = l[r][j];

    // Softmax / argmax / loss per vox (wave-local: this wave wrote all co)
    #pragma unroll
    for (int r = 0; r < 4; ++r) {
        float m = l[r][0]; int mi = lane;
        #pragma unroll
        for (int j = 1; j < 8; ++j)
            if (l[r][j] > m) { m = l[r][j]; mi = j*64 + lane; }
        #pragma unroll
        for (int o = 32; o > 0; o >>= 1) {
            float om = __shfl_down(m, o, 64);
            int   oi = __shfl_down(mi, o, 64);
            if (om > m || (om == m && oi < mi)) { m = om; mi = oi; }
        }
        float maxv = __shfl(m, 0, 64);
        int   maxi = __shfl(mi, 0, 64);
        float es = 0.f;
        #pragma unroll
        for (int j = 0; j < 8; ++j) es += __expf(l[r][j] - maxv);
        float sum = wred_sum(es);
        if (lane == 0) {
            int vox = vox0 + wid*4 + r;
            int target = ncode[(n*3 + sn)*512 + vox];
            float logp = lg[target*20 + wid*4 + r] - maxv - __logf(sum);
            atomicAdd(out + 1572864, -logp * (1.f/3072.f));
            out[1572865 + (n*3 + sn)*512 + vox] = (float)maxi;
        }
    }

    __syncthreads();
    for (int e = t; e < 2048; e += 256) {     // full 64B-line score writes
        int co = e >> 2, p = e & 3;
        int base = co*20 + p*4;
        float4 o4 = { lg[base], lg[base+1], lg[base+2], lg[base+3] };
        *(float4*)(out + (size_t)((n*512 + co)*3 + sn)*512 + vox0 + p*4) = o4;
    }
}

extern "C" void kernel_launch(void* const* d_in, const int* in_sizes, int n_in,
                              void* d_out, int out_size, void* d_ws, size_t ws_size,
                              hipStream_t stream) {
    (void)in_sizes; (void)n_in; (void)out_size; (void)ws_size;
    const int*   code  = (const int*)d_in[0];
    const int*   ncode = (const int*)d_in[1];
    const float* emb   = (const float*)d_in[2];
    const float* win   = (const float*)d_in[3];
    const float* bin_  = (const float*)d_in[4];
    const float* gin_w = (const float*)d_in[5];
    const float* gin_b = (const float*)d_in[6];
    const float* wh    = (const float*)d_in[7];
    const float* bh    = (const float*)d_in[8];
    const float* gh_w  = (const float*)d_in[9];
    const float* gh_b  = (const float*)d_in[10];
    const float* w1    = (const float*)d_in[11];
    const float* b1    = (const float*)d_in[12];
    const float* ln_g  = (const float*)d_in[13];
    const float* ln_b  = (const float*)d_in[14];
    const float* w2    = (const float*)d_in[15];
    const float* b2    = (const float*)d_in[16];
    float* out = (float*)d_out;

    float* base  = (float*)d_ws;
    f16*   wp    = (f16*)base;                    // 4*884736 halfs = 1,769,472 f
    f16*   h1    = (f16*)(base + 1769472);        // [2][7][512][128] hi/lo
    f16*   h2    = h1 + 917504;
    float* gi1   = base + 2686976;                // 2 partials x 262144
    float* gi2   = gi1 + 2*GPART;
    float* ghat1 = gi2 + 2*GPART;
    float* ghat2 = ghat1 + 2*GPART;
    float* cx1   = ghat2 + 2*GPART;               // [2][512][64]
    float* cx2   = cx1 + 65536;                   // end: 4,915,200 floats (~19.7MB)

    const f16* win0 = wp;
    const f16* wh0  = wp + WPT;
    const f16* win1 = wp + 2*WPT;
    const f16* wh1  = wp + 3*WPT;

    hipMemsetAsync(out + 1572864, 0, sizeof(float), stream);   // loss accumulator
    embed_kernel<<<1792, 256, 0, stream>>>(code, ncode, emb, h1);
    wsplit_kernel<<<108, 256, 0, stream>>>(win, wh, wp);

    // pre-loop: gi1(0) = conv(emb h1[0], win0)
    {
        MJobs js{};
        js.j[0] = { h1, win0, gi1 };
        conv_mfma_kernel<<<dim3(128, 1), 256, 0, stream>>>(js);
    }

    for (int s = 0; s <= 7; ++s) {
        // ---- gates: gates1(s) [s<=6], gates2(s-1) [s>=1] ----
        GJob g1 = { gi1, gi1 + GPART, ghat1, ghat1 + GPART, bin_, bh,
                    gin_w, gin_b, gh_w, gh_b, cx1, h1, s, s == 0 };
        GJob g2 = { gi2, gi2 + GPART, ghat2, ghat2 + GPART, bin_ + 256, bh + 256,
                    gin_w + 256, gin_b + 256, gh_w + 256, gh_b + 256,
                    cx2, h2, s - 1, s == 1 };
        if (s == 0)
            gates_step_kernel<<<dim3(256, 1), 256, 0, stream>>>(g1, g1);
        else if (s <= 6)
            gates_step_kernel<<<dim3(256, 2), 256, 0, stream>>>(g1, g2);
        else
            gates_step_kernel<<<dim3(256, 1), 256, 0, stream>>>(g2, g2);

        // ---- convs: in1(s+1), rec1(s), in2(s), rec2(s) ----
        MJobs js{}; int nj = 0;
        if (s <= 5) js.j[nj++] = { h1 + (size_t)(s+1)*XSP, win0, gi1 };
        if (s <= 5) js.j[nj++] = { h1 + (size_t)s*XSP,     wh0,  ghat1 };
        if (s <= 6) js.j[nj++] = { h1 + (size_t)s*XSP,     win1, gi2 };
        if (s >= 1 && s <= 6)
                    js.j[nj++] = { h2 + (size_t)(s-1)*XSP, wh1,  ghat2 };
        if (nj > 0)
            conv_mfma_kernel<<<dim3(128, nj), 256, 0, stream>>>(js);
    }

    head_kernel<<<192, 256, 0, stream>>>(h2, w1, b1, ln_g, ln_b, w2, b2, ncode, out);
}

// Round 4
// 305.041 us; speedup vs baseline: 1.1014x; 1.1014x over previous
//
#include <hip/hip_runtime.h>

// r18: two fixes driven by the r17 falsification:
//  (a) head_kernel was pinned at 60-65us in BOTH r16/r17 structures with all
//      pipes ~idle -> the invariant is 3072 same-address loss atomicAdds
//      (~20ns each serialized = ~60us). Now: LDS-reduce 16 per-block terms,
//      ONE atomicAdd per block (192 total).
//  (b) conv: r17's K-split x2 was LDS-capped at 2 blocks/CU (64KB). Split M
//      (a-half, 32 vox) instead of more K: grid/job 128->256, acc 4x4->2x4,
//      single-buffered 8KB/wave staging + 32KB reduce => LDS 32KB total ->
//      3 resident blocks/CU at nj=3. Partials stay 2 (gates/ws unchanged).
//  (c) embed+wsplit merged into one prep launch.
// Numerics unchanged: 3-segment hi/lo f16 MFMA (fp32-grade, ~2^-22).

typedef _Float16 f16;
typedef _Float16 f16x8 __attribute__((ext_vector_type(8)));
typedef float    f32x4 __attribute__((ext_vector_type(4)));

#define WSTRIDE 442368   // fp32 weight elements per layer: 27*64*256
#define WPT     884736   // halfs per packed tensor: 54*256*64
#define XSP     65536    // halfs per s-slab of h: 512*128
#define HSP     458752   // halfs per nc of h: 7*512*128
#define GPART   262144   // floats per conv partial buffer: 2*512*256

__device__ __forceinline__ float wred_sum(float v) {
    #pragma unroll
    for (int o = 32; o > 0; o >>= 1) v += __shfl_down(v, o, 64);
    return __shfl(v, 0, 64);
}
__device__ __forceinline__ float fsig(float x)  { return 1.f / (1.f + __expf(-x)); }
__device__ __forceinline__ float ftanh(float x) { return 1.f - 2.f / (__expf(2.f*x) + 1.f); }

// prep: blocks [0,1792) embed h1 hi/lo; blocks [1792,1900) pack weights.
__global__ __launch_bounds__(256) void prep_kernel(
    const int* __restrict__ code, const int* __restrict__ ncode,
    const float* __restrict__ emb, f16* __restrict__ h,
    const float* __restrict__ win, const float* __restrict__ wh,
    f16* __restrict__ wp)
{
    if (blockIdx.x < 1792) {
        int e = blockIdx.x * 256 + threadIdx.x;   // < 458752
        int ch = e & 63;
        int pos = e >> 6;            // nc*7*512 + s*512 + vox
        int vox = pos & 511;
        int t = pos >> 9;
        int s = t % 7, nc = t / 7;
        int tok = (s < 5) ? code[(nc*5 + s)*512 + vox]
                          : ncode[(nc*3 + (s-5))*512 + vox];
        float x = emb[tok*64 + ch];
        f16 hi = (f16)x;
        h[(size_t)pos*128 + ch]      = hi;
        h[(size_t)pos*128 + 64 + ch] = (f16)(x - (float)hi);
    } else {
        // pack: src [27][64 ci][256 co] fp32 -> per K-atom (tap, ci-half)
        // [54][256 co][8 chunks][8] f16; hi chunk j at (j ^ (co&7)), lo at
        // ((4+j) ^ (co&7)); values x64. Order: win0, wh0, win1, wh1.
        int b = blockIdx.x - 1792;        // 108 = 4 tensors * 27 taps
        int tensor = b / 27, tap = b % 27;
        const float* src = ((tensor & 1) ? wh : win) + (tensor >> 1) * WSTRIDE
                         + tap * 16384;
        int co = threadIdx.x;
        int sw = co & 7;
        #pragma unroll
        for (int hs = 0; hs < 2; ++hs) {
            f16* dst = wp + (((size_t)tensor*27 + tap)*2 + hs)*16384 + co*64;
            #pragma unroll
            for (int j = 0; j < 4; ++j) {
                f16x8 hi8, lo8;
                #pragma unroll
                for (int m = 0; m < 8; ++m) {
                    float w = src[(hs*32 + j*8 + m)*256 + co] * 64.f;
                    f16 hv = (f16)w;
                    hi8[m] = hv;
                    lo8[m] = (f16)(w - (float)hv);
                }
                *(f16x8*)(dst + ((j     ^ sw))*8) = hi8;
                *(f16x8*)(dst + (((4+j) ^ sw))*8) = lo8;
            }
        }
    }
}

struct MJob { const f16* x; const f16* w; float* y; };
struct MJobs { MJob j[4]; };

// One 3x3x3 SAME conv job (Cin=64 -> Cout=256), implicit GEMM, 3-segment
// hi/lo f16 MFMA. grid.x = 256/job: [kb(2)|ah(2)|slab(2)|u(8)|cog(4)].
// Block covers a 32-vox a-half x 64 co; 54 K-atoms split over 8 groups
// (kb*4+wid, {7x6,6x2}); each wave stages its atom tile (8KB, single-buffered
// -- same-wave LDS is in-order) into a private region. A-frags straight from
// global with halo predication. One barrier; in-block 4-way K-reduce in the
// same 32KB; partial written to y + kb*GPART (no bias).
__global__ __launch_bounds__(256, 3) void conv_mfma_kernel(MJobs js)
{
    const MJob J = js.j[blockIdx.y];
    __shared__ float4 smem[2048];          // 32 KiB
    f16* wbuf = (f16*)smem;

    const int bx = blockIdx.x;
    const int cog = bx & 3, u = (bx >> 2) & 7, slab = (bx >> 5) & 1;
    const int ah = (bx >> 6) & 1, kb = bx >> 7;
    const int t = threadIdx.x, wid = t >> 6, l = t & 63;
    const int lv = (l >> 3) & 1, lw = l & 7, khi = l >> 4;

    const int gid = kb*4 + wid;
    const int g0  = (gid < 6) ? gid*7 : 42 + (gid - 6)*6;
    const int cnt = (gid < 6) ? 7 : 6;

    const f16* xbase = J.x + (size_t)slab * HSP;
    const f16* wjob  = J.w + (size_t)cog * 4096;      // + atom*16384
    f16* wmine = wbuf + wid * 4096;                   // 8KB, single-buffered

    f16x8 wreg[8];
    auto wload = [&](int k) {             // global -> regs (linear, coalesced)
        const f16* src = wjob + (size_t)k * 16384 + l * 8;
        #pragma unroll
        for (int i = 0; i < 8; ++i) wreg[i] = *(const f16x8*)(src + i * 512);
    };
    auto wstore = [&]() {                 // regs -> LDS (linear)
        f16* dst = wmine + l * 8;
        #pragma unroll
        for (int i = 0; i < 8; ++i) *(f16x8*)(dst + i * 512) = wreg[i];
    };

    wload(g0); wstore();

    f32x4 acc[2][4] = {};                 // [aa: vox 16-tile][n: co 16-tile]
    for (int q = 0; q < cnt; ++q) {
        const int k = g0 + q;
        if (q + 1 < cnt) wload(k + 1);              // prefetch next atom
        const int tap = k >> 1, hs = k & 1;
        const int du = tap / 9, rr = tap % 9, dv = rr / 3, dw = rr % 3;
        const int uu = u + du - 1;
        const bool uok = (unsigned)uu < 8u;
        const f16* xrow[2]; bool ok[2];
        #pragma unroll
        for (int aa = 0; aa < 2; ++aa) {            // vox = (ah*2+aa)*16 + (l&15)
            int vs = (ah*2 + aa)*2 + lv + dv - 1, ws = lw + dw - 1;
            ok[aa] = uok && (unsigned)vs < 8u && (unsigned)ws < 8u;
            xrow[aa] = xbase + ((size_t)(uu*64 + vs*8 + ws) << 7) + khi*8;
        }
        const f16* wrow = wmine + (l & 15)*64;
        const int schi = ((khi    ) ^ lw) * 8;
        const int sclo = ((4 + khi) ^ lw) * 8;
        f16x8 ahi[2], alo[2], bhi[4], blo[4];
        #pragma unroll
        for (int aa = 0; aa < 2; ++aa) {
            f16x8 v = {0,0,0,0,0,0,0,0}, v2 = v;
            if (ok[aa]) {
                v  = *(const f16x8*)(xrow[aa] + hs*32);
                v2 = *(const f16x8*)(xrow[aa] + 64 + hs*32);
            }
            ahi[aa] = v; alo[aa] = v2;
        }
        #pragma unroll
        for (int n = 0; n < 4; ++n) {
            bhi[n] = *(const f16x8*)(wrow + n*1024 + schi);
            blo[n] = *(const f16x8*)(wrow + n*1024 + sclo);
        }
        #pragma unroll
        for (int aa = 0; aa < 2; ++aa)
            #pragma unroll
            for (int n = 0; n < 4; ++n)
                acc[aa][n] = __builtin_amdgcn_mfma_f32_16x16x32_f16(
                    ahi[aa], bhi[n], acc[aa][n], 0, 0, 0);
        #pragma unroll
        for (int aa = 0; aa < 2; ++aa)
            #pragma unroll
            for (int n = 0; n < 4; ++n)
                acc[aa][n] = __builtin_amdgcn_mfma_f32_16x16x32_f16(
                    alo[aa], bhi[n], acc[aa][n], 0, 0, 0);
        #pragma unroll
        for (int aa = 0; aa < 2; ++aa)
            #pragma unroll
            for (int n = 0; n < 4; ++n)
                acc[aa][n] = __builtin_amdgcn_mfma_f32_16x16x32_f16(
                    ahi[aa], blo[n], acc[aa][n], 0, 0, 0);
        if (q + 1 < cnt) wstore();                  // own region; wave-ordered
    }

    // In-block 4-way K-reduce: each wave dumps into its OWN 8KB region
    // (chunk ^ (l&7) spreads the 128B lane stride over all banks).
    f32x4* red = (f32x4*)smem;
    {
        f32x4* mine = red + (size_t)(wid * 64 + l) * 8;
        #pragma unroll
        for (int aa = 0; aa < 2; ++aa)
            #pragma unroll
            for (int n = 0; n < 4; ++n)
                mine[(aa * 4 + n) ^ lw] = acc[aa][n];
    }
    __syncthreads();
    {
        float* yp = J.y + (size_t)kb * GPART;
        const int aa = (t >> 7) & 1, nsel = (t >> 6) & 1, ll = t & 63;
        #pragma unroll
        for (int ni = 0; ni < 2; ++ni) {
            const int n = nsel*2 + ni;
            const int ch = (aa * 4 + n) ^ (ll & 7);
            f32x4 sv = red[(0 * 64 + ll) * 8 + ch]
                     + red[(1 * 64 + ll) * 8 + ch]
                     + red[(2 * 64 + ll) * 8 + ch]
                     + red[(3 * 64 + ll) * 8 + ch];
            const int co = cog * 64 + n * 16 + (ll & 15);
            #pragma unroll
            for (int r = 0; r < 4; ++r) {           // D row = 4*(ll>>4)+r
                int vox = (ah*2 + aa) * 16 + (ll >> 4) * 4 + r;
                yp[(size_t)(slab * 512 + u * 64 + vox) * 256 + co]
                    = sv[r] * 0.015625f;            // /64 (w' scale)
            }
        }
    }
}

// Dual-LN LSTM cell (fp32). Sums the two conv partials + bias per path.
struct GJob {
    const float* giA; const float* giB;
    const float* ghA; const float* ghB;
    const float* bin; const float* bhb;
    const float* ginw; const float* ginb;
    const float* ghw;  const float* ghb;
    float* cx; f16* h16; int k; int k0;
};
__global__ __launch_bounds__(256) void gates_step_kernel(GJob ja, GJob jb)
{
    const GJob J = (blockIdx.y == 0) ? ja : jb;
    const int wid = threadIdx.x >> 6, lane = threadIdx.x & 63;
    const int row = blockIdx.x * 4 + wid;     // nc*512 + vox, < 1024
    const int nc = row >> 9, vox = row & 511;

    const float* gA = J.giA + (size_t)row*256;
    const float* gB = J.giB + (size_t)row*256;
    float a0 = gA[lane]     + gB[lane]     + J.bin[lane];
    float a1 = gA[64+lane]  + gB[64+lane]  + J.bin[64+lane];
    float a2 = gA[128+lane] + gB[128+lane] + J.bin[128+lane];
    float a3 = gA[192+lane] + gB[192+lane] + J.bin[192+lane];
    float mu1 = wred_sum(a0+a1+a2+a3) * (1.f/256.f);
    float d0=a0-mu1, d1=a1-mu1, d2=a2-mu1, d3=a3-mu1;
    float v1 = wred_sum(d0*d0+d1*d1+d2*d2+d3*d3) * (1.f/256.f);
    float rs1 = rsqrtf(v1 + 1e-5f);

    float b0, b1, b2, b3;
    if (J.k0) {
        b0 = J.bhb[lane]; b1 = J.bhb[64+lane];
        b2 = J.bhb[128+lane]; b3 = J.bhb[192+lane];
    } else {
        const float* hA = J.ghA + (size_t)row*256;
        const float* hB = J.ghB + (size_t)row*256;
        b0 = hA[lane]     + hB[lane]     + J.bhb[lane];
        b1 = hA[64+lane]  + hB[64+lane]  + J.bhb[64+lane];
        b2 = hA[128+lane] + hB[128+lane] + J.bhb[128+lane];
        b3 = hA[192+lane] + hB[192+lane] + J.bhb[192+lane];
    }
    float mu2 = wred_sum(b0+b1+b2+b3) * (1.f/256.f);
    float e0=b0-mu2, e1=b1-mu2, e2=b2-mu2, e3=b3-mu2;
    float v2 = wred_sum(e0*e0+e1*e1+e2*e2+e3*e3) * (1.f/256.f);
    float rs2 = rsqrtf(v2 + 1e-5f);

    float Ig = d0*rs1*J.ginw[lane]     + J.ginb[lane]     + e0*rs2*J.ghw[lane]     + J.ghb[lane];
    float Fg = d1*rs1*J.ginw[64+lane]  + J.ginb[64+lane]  + e1*rs2*J.ghw[64+lane]  + J.ghb[64+lane];
    float Cg = d2*rs1*J.ginw[128+lane] + J.ginb[128+lane] + e2*rs2*J.ghw[128+lane] + J.ghb[128+lane];
    float Og = d3*rs1*J.ginw[192+lane] + J.ginb[192+lane] + e3*rs2*J.ghw[192+lane] + J.ghb[192+lane];

    float c_old = J.k0 ? 0.f : J.cx[(size_t)row*64 + lane];
    float c_new = fsig(Fg)*c_old + fsig(Ig)*ftanh(Cg);
    float h_new = fsig(Og)*ftanh(c_new);
    J.cx[(size_t)row*64 + lane] = c_new;
    size_t hb = ((size_t)(nc*7 + J.k)*512 + vox)*128 + lane;
    f16 hi = (f16)h_new;
    J.h16[hb]      = hi;
    J.h16[hb + 64] = (f16)(h_new - (float)hi);
}

// Head: 192 blocks x 16 vox (4 per wave). Loss: LDS-reduced, ONE atomic per
// block (was 16 -> 3072 same-line atomics device-wide = the 60us floor).
__global__ __launch_bounds__(256) void head_kernel(
    const f16* __restrict__ h,        // [2][7][512][128] hi/lo
    const float* __restrict__ w1, const float* __restrict__ b1,
    const float* __restrict__ lng, const float* __restrict__ lnb,
    const float* __restrict__ w2, const float* __restrict__ b2,
    const int* __restrict__ ncode,
    float* __restrict__ out)
{
    __shared__ float hsm[16][64];
    __shared__ float zv[16][64];
    __shared__ float lg[10240];               // [512 co][16 vox] stride 20
    __shared__ float lsum[16];
    const int blk = blockIdx.x;               // 192 = n(2) x sn(3) x vg(32)
    const int n = blk / 96;
    const int sn = (blk / 32) % 3;
    const int vox0 = (blk & 31) * 16;
    const int t = threadIdx.x, wid = t >> 6, lane = t & 63;

    for (int idx = t; idx < 1024; idx += 256) {
        int vr = idx >> 6, ch = idx & 63;
        const f16* hv = h + (size_t)((n*7 + sn + 4)*512 + vox0 + vr)*128;
        hsm[vr][ch] = (float)hv[ch] + (float)hv[64 + ch];
    }
    __syncthreads();

    // GEMV1 (h @ w1 + b1) for this wave's 4 vox, dual accumulators
    float yva[4], yvb[4];
    #pragma unroll
    for (int r = 0; r < 4; ++r) { yva[r] = b1[lane]; yvb[r] = 0.f; }
    for (int kk = 0; kk < 64; kk += 2) {
        float w1a = w1[kk*64 + lane], w1b = w1[(kk+1)*64 + lane];
        #pragma unroll
        for (int r = 0; r < 4; ++r) {
            yva[r] = fmaf(hsm[wid*4 + r][kk],     w1a, yva[r]);
            yvb[r] = fmaf(hsm[wid*4 + r][kk + 1], w1b, yvb[r]);
        }
    }
    #pragma unroll
    for (int r = 0; r < 4; ++r) {
        float yv = yva[r] + yvb[r];
        float mu = wred_sum(yv) * (1.f/64.f);
        float d = yv - mu;
        float var = wred_sum(d*d) * (1.f/64.f);
        float ln = d * rsqrtf(var + 1e-5f) * lng[lane] + lnb[lane];
        zv[wid*4 + r][lane] = 0.5f * ln * (1.f + erff(ln * 0.70710678118654752f));
    }
    __syncthreads();

    // GEMM2: logits[4 vox][512 co]
    float l[4][8];
    #pragma unroll
    for (int r = 0; r < 4; ++r)
        #pragma unroll
        for (int j = 0; j < 8; ++j) l[r][j] = b2[j*64 + lane];
    for (int kk = 0; kk < 64; ++kk) {
        float wv[8];
        #pragma unroll
        for (int j = 0; j < 8; ++j) wv[j] = w2[kk*512 + j*64 + lane];
        #pragma unroll
        for (int r = 0; r < 4; ++r) {
            float zz = zv[wid*4 + r][kk];
            #pragma unroll
            for (int j = 0; j < 8; ++j) l[r][j] = fmaf(zz, wv[j], l[r][j]);
        }
    }
    #pragma unroll
    for (int r = 0; r < 4; ++r)
        #pragma unroll
        for (int j = 0; j < 8; ++j)
            lg[(j*64 + lane)*20 + wid*4 + r] = l[r][j];

    // Softmax / argmax / loss per vox (wave-local: this wave wrote all co)
    #pragma unroll
    for (int r = 0; r < 4; ++r) {
        float m = l[r][0]; int mi = lane;
        #pragma unroll
        for (int j = 1; j < 8; ++j)
            if (l[r][j] > m) { m = l[r][j]; mi = j*64 + lane; }
        #pragma unroll
        for (int o = 32; o > 0; o >>= 1) {
            float om = __shfl_down(m, o, 64);
            int   oi = __shfl_down(mi, o, 64);
            if (om > m || (om == m && oi < mi)) { m = om; mi = oi; }
        }
        float maxv = __shfl(m, 0, 64);
        int   maxi = __shfl(mi, 0, 64);
        float es = 0.f;
        #pragma unroll
        for (int j = 0; j < 8; ++j) es += __expf(l[r][j] - maxv);
        float sum = wred_sum(es);
        if (lane == 0) {
            int vox = vox0 + wid*4 + r;
            int target = ncode[(n*3 + sn)*512 + vox];
            float logp = lg[target*20 + wid*4 + r] - maxv - __logf(sum);
            lsum[wid*4 + r] = -logp * (1.f/3072.f);
            out[1572865 + (n*3 + sn)*512 + vox] = (float)maxi;
        }
    }

    __syncthreads();
    if (t == 0) {                             // ONE loss atomic per block
        float s = 0.f;
        #pragma unroll
        for (int i = 0; i < 16; ++i) s += lsum[i];
        atomicAdd(out + 1572864, s);
    }
    for (int e = t; e < 2048; e += 256) {     // full 64B-line score writes
        int co = e >> 2, p = e & 3;
        int base = co*20 + p*4;
        float4 o4 = { lg[base], lg[base+1], lg[base+2], lg[base+3] };
        *(float4*)(out + (size_t)((n*512 + co)*3 + sn)*512 + vox0 + p*4) = o4;
    }
}

extern "C" void kernel_launch(void* const* d_in, const int* in_sizes, int n_in,
                              void* d_out, int out_size, void* d_ws, size_t ws_size,
                              hipStream_t stream) {
    (void)in_sizes; (void)n_in; (void)out_size; (void)ws_size;
    const int*   code  = (const int*)d_in[0];
    const int*   ncode = (const int*)d_in[1];
    const float* emb   = (const float*)d_in[2];
    const float* win   = (const float*)d_in[3];
    const float* bin_  = (const float*)d_in[4];
    const float* gin_w = (const float*)d_in[5];
    const float* gin_b = (const float*)d_in[6];
    const float* wh    = (const float*)d_in[7];
    const float* bh    = (const float*)d_in[8];
    const float* gh_w  = (const float*)d_in[9];
    const float* gh_b  = (const float*)d_in[10];
    const float* w1    = (const float*)d_in[11];
    const float* b1    = (const float*)d_in[12];
    const float* ln_g  = (const float*)d_in[13];
    const float* ln_b  = (const float*)d_in[14];
    const float* w2    = (const float*)d_in[15];
    const float* b2    = (const float*)d_in[16];
    float* out = (float*)d_out;

    float* base  = (float*)d_ws;
    f16*   wp    = (f16*)base;                    // 4*884736 halfs = 1,769,472 f
    f16*   h1    = (f16*)(base + 1769472);        // [2][7][512][128] hi/lo
    f16*   h2    = h1 + 917504;
    float* gi1   = base + 2686976;                // 2 partials x 262144
    float* gi2   = gi1 + 2*GPART;
    float* ghat1 = gi2 + 2*GPART;
    float* ghat2 = ghat1 + 2*GPART;
    float* cx1   = ghat2 + 2*GPART;               // [2][512][64]
    float* cx2   = cx1 + 65536;                   // end: 4,915,200 floats (~19.7MB)

    const f16* win0 = wp;
    const f16* wh0  = wp + WPT;
    const f16* win1 = wp + 2*WPT;
    const f16* wh1  = wp + 3*WPT;

    hipMemsetAsync(out + 1572864, 0, sizeof(float), stream);   // loss accumulator
    prep_kernel<<<1900, 256, 0, stream>>>(code, ncode, emb, h1, win, wh, wp);

    // pre-loop: gi1(0) = conv(emb h1[0], win0)
    {
        MJobs js{};
        js.j[0] = { h1, win0, gi1 };
        conv_mfma_kernel<<<dim3(256, 1), 256, 0, stream>>>(js);
    }

    for (int s = 0; s <= 7; ++s) {
        // ---- gates: gates1(s) [s<=6], gates2(s-1) [s>=1] ----
        GJob g1 = { gi1, gi1 + GPART, ghat1, ghat1 + GPART, bin_, bh,
                    gin_w, gin_b, gh_w, gh_b, cx1, h1, s, s == 0 };
        GJob g2 = { gi2, gi2 + GPART, ghat2, ghat2 + GPART, bin_ + 256, bh + 256,
                    gin_w + 256, gin_b + 256, gh_w + 256, gh_b + 256,
                    cx2, h2, s - 1, s == 1 };
        if (s == 0)
            gates_step_kernel<<<dim3(256, 1), 256, 0, stream>>>(g1, g1);
        else if (s <= 6)
            gates_step_kernel<<<dim3(256, 2), 256, 0, stream>>>(g1, g2);
        else
            gates_step_kernel<<<dim3(256, 1), 256, 0, stream>>>(g2, g2);

        // ---- convs: in1(s+1), rec1(s), in2(s), rec2(s) ----
        MJobs js{}; int nj = 0;
        if (s <= 5) js.j[nj++] = { h1 + (size_t)(s+1)*XSP, win0, gi1 };
        if (s <= 5) js.j[nj++] = { h1 + (size_t)s*XSP,     wh0,  ghat1 };
        if (s <= 6) js.j[nj++] = { h1 + (size_t)s*XSP,     win1, gi2 };
        if (s >= 1 && s <= 6)
                    js.j[nj++] = { h2 + (size_t)(s-1)*XSP, wh1,  ghat2 };
        if (nj > 0)
            conv_mfma_kernel<<<dim3(256, nj), 256, 0, stream>>>(js);
    }

    head_kernel<<<192, 256, 0, stream>>>(h2, w1, b1, ln_g, ln_b, w2, b2, ncode, out);
}